// Round 1
// baseline (445.613 us; speedup 1.0000x reference)
//
#include <hip/hip_runtime.h>
#include <math.h>

#define NQ   11
#define DIM  2048        // 2^11
#define NL   6
#define NG   (NL*NQ)     // 66 fused gates
#define BLK  256
#define PAIRS (DIM/2)    // 1024
#define PPT  (PAIRS/BLK) // 4 pairs per thread

__global__ __launch_bounds__(BLK) void qnn_kernel(
    const float* __restrict__ X,      // (B, NQ)
    const float* __restrict__ P,      // (NL, NQ, 3)
    float2* __restrict__ out)         // (B, DIM) as (re, im)
{
    __shared__ float2 st[DIM];        // state vector, 16 KB
    __shared__ float2 G[NG][4];       // fused gate matrices U00,U01,U10,U11

    const int b   = blockIdx.x;
    const int tid = threadIdx.x;

    // ---- init |0...0> ----
    for (int i = tid; i < DIM; i += BLK) st[i] = make_float2(0.f, 0.f);
    if (tid == 0) st[0] = make_float2(1.f, 0.f);

    // ---- build fused gate table (threads 0..65) ----
    // U = RZ(p2) * RY(p1) * RZ(p0)
    //   = [[c e^{-ia}, -s e^{ib}], [s e^{-ib}, c e^{ia}]],
    //   a=(p0+p2)/2, b=(p0-p2)/2, c=cos(p1/2), s=sin(p1/2)
    // last layer: V = RY(x_q) * U  (data re-upload)
    if (tid < NG) {
        const int l = tid / NQ, q = tid % NQ;
        const float p0 = P[tid*3+0], p1 = P[tid*3+1], p2 = P[tid*3+2];
        const float t  = 0.5f*p1;
        const float c  = cosf(t),  s  = sinf(t);
        const float al = 0.5f*(p0+p2), be = 0.5f*(p0-p2);
        const float ca = cosf(al), sa = sinf(al);
        const float cb = cosf(be), sb = sinf(be);
        float2 U00 = make_float2( c*ca, -c*sa);
        float2 U01 = make_float2(-s*cb, -s*sb);
        float2 U10 = make_float2( s*cb, -s*sb);
        float2 U11 = make_float2( c*ca,  c*sa);
        if (l == NL-1) {
            const float tx = 0.5f * X[(size_t)b*NQ + q];
            const float cx = cosf(tx), sx = sinf(tx);
            float2 V00 = make_float2(cx*U00.x - sx*U10.x, cx*U00.y - sx*U10.y);
            float2 V01 = make_float2(cx*U01.x - sx*U11.x, cx*U01.y - sx*U11.y);
            float2 V10 = make_float2(sx*U00.x + cx*U10.x, sx*U00.y + cx*U10.y);
            float2 V11 = make_float2(sx*U01.x + cx*U11.x, sx*U01.y + cx*U11.y);
            U00 = V00; U01 = V01; U10 = V10; U11 = V11;
        }
        G[tid][0] = U00; G[tid][1] = U01; G[tid][2] = U10; G[tid][3] = U11;
    }
    __syncthreads();

    for (int l = 0; l < NL; ++l) {
        // ---- 11 fused single-qubit gates ----
        for (int q = 0; q < NQ; ++q) {
            const int g = l*NQ + q;
            const float2 U00 = G[g][0], U01 = G[g][1], U10 = G[g][2], U11 = G[g][3];
            const int p    = NQ - 1 - q;   // bit position of qubit q (q0 = MSB)
            const int mask = 1 << p;
            #pragma unroll
            for (int k = 0; k < PPT; ++k) {
                const int j  = tid + k*BLK;                    // pair index
                const int i0 = ((j >> p) << (p+1)) | (j & (mask-1));
                const int i1 = i0 | mask;
                const float2 a0 = st[i0], a1 = st[i1];
                float2 n0, n1;
                n0.x = U00.x*a0.x - U00.y*a0.y + U01.x*a1.x - U01.y*a1.y;
                n0.y = U00.x*a0.y + U00.y*a0.x + U01.x*a1.y + U01.y*a1.x;
                n1.x = U10.x*a0.x - U10.y*a0.y + U11.x*a1.x - U11.y*a1.y;
                n1.y = U10.x*a0.y + U10.y*a0.x + U11.x*a1.y + U11.y*a1.x;
                st[i0] = n0; st[i1] = n1;
            }
            __syncthreads();
        }
        // ---- CNOT chain c=0..9 composes to: amp at i moves to prefix-XOR f(i) ----
        float2 v[DIM/BLK];
        #pragma unroll
        for (int k = 0; k < DIM/BLK; ++k) v[k] = st[tid + k*BLK];
        __syncthreads();
        #pragma unroll
        for (int k = 0; k < DIM/BLK; ++k) {
            const int i = tid + k*BLK;
            int f = i;
            f ^= f >> 1; f ^= f >> 2; f ^= f >> 4; f ^= f >> 8;
            st[f] = v[k];
        }
        __syncthreads();
    }

    // ---- write (B, DIM, 2) float32 = float2 per amplitude ----
    float2* o = out + (size_t)b * DIM;
    for (int i = tid; i < DIM; i += BLK) o[i] = st[i];
}

extern "C" void kernel_launch(void* const* d_in, const int* in_sizes, int n_in,
                              void* d_out, int out_size, void* d_ws, size_t ws_size,
                              hipStream_t stream) {
    const float* X = (const float*)d_in[0];   // (B, NQ) float32
    const float* P = (const float*)d_in[1];   // (NL, NQ, 3) float32
    float2* out = (float2*)d_out;             // (B, DIM, 2) float32
    const int B = in_sizes[0] / NQ;           // 8192
    qnn_kernel<<<B, BLK, 0, stream>>>(X, P, out);
}

// Round 2
// 115.970 us; speedup vs baseline: 3.8425x; 3.8425x over previous
//
#include <hip/hip_runtime.h>
#include <math.h>

#define NQ   11
#define DIM  2048        // 2^11
#define NL   6
#define BLK  256

__device__ __forceinline__ int sw(int i) {
    // XOR swizzle: s0=i0^i7, s1=i1^i4^i8, s2=i2^i5, s3=i3^i6 (bijective)
    return i ^ ((i & 0x70) >> 3) ^ ((i >> 7) & 3);
}

__device__ __forceinline__ float2 cfma2(float2 u, float2 a, float2 v, float2 b) {
    // complex u*a + v*b
    float2 r;
    r.x = u.x*a.x - u.y*a.y + v.x*b.x - v.y*b.y;
    r.y = u.x*a.y + u.y*a.x + v.x*b.y + v.y*b.x;
    return r;
}

// ---------------- kernel 1: shared layers 0..4 (sample-independent), 1 block ----
__global__ __launch_bounds__(BLK) void qnn_shared_kernel(
    const float* __restrict__ P,      // (NL, NQ, 3)
    float2* __restrict__ ws)          // out: state after layer 4 (+perm), 2048 float2
{
    __shared__ float2 st[DIM];
    __shared__ float2 G[(NL-1)*NQ][4];
    const int tid = threadIdx.x;

    for (int i = tid; i < DIM; i += BLK) st[i] = make_float2(0.f, 0.f);
    if (tid == 0) st[0] = make_float2(1.f, 0.f);

    if (tid < (NL-1)*NQ) {
        const float p0 = P[tid*3+0], p1 = P[tid*3+1], p2 = P[tid*3+2];
        const float t  = 0.5f*p1;
        const float c  = cosf(t),  s  = sinf(t);
        const float al = 0.5f*(p0+p2), be = 0.5f*(p0-p2);
        const float ca = cosf(al), sa = sinf(al);
        const float cb = cosf(be), sb = sinf(be);
        G[tid][0] = make_float2( c*ca, -c*sa);
        G[tid][1] = make_float2(-s*cb, -s*sb);
        G[tid][2] = make_float2( s*cb, -s*sb);
        G[tid][3] = make_float2( c*ca,  c*sa);
    }
    __syncthreads();

    for (int l = 0; l < NL-1; ++l) {
        for (int q = 0; q < NQ; ++q) {
            const int g = l*NQ + q;
            const float2 U00 = G[g][0], U01 = G[g][1], U10 = G[g][2], U11 = G[g][3];
            const int p    = NQ - 1 - q;
            const int mask = 1 << p;
            #pragma unroll
            for (int k = 0; k < 4; ++k) {
                const int j  = tid + k*BLK;
                const int i0 = ((j >> p) << (p+1)) | (j & (mask-1));
                const int i1 = i0 | mask;
                const float2 a0 = st[i0], a1 = st[i1];
                st[i0] = cfma2(U00, a0, U01, a1);
                st[i1] = cfma2(U10, a0, U11, a1);
            }
            __syncthreads();
        }
        // CNOT chain: amp at i moves to prefix-XOR f(i)
        float2 v[DIM/BLK];
        #pragma unroll
        for (int k = 0; k < DIM/BLK; ++k) v[k] = st[tid + k*BLK];
        __syncthreads();
        #pragma unroll
        for (int k = 0; k < DIM/BLK; ++k) {
            const int i = tid + k*BLK;
            int f = i;
            f ^= f >> 1; f ^= f >> 2; f ^= f >> 4; f ^= f >> 8;
            st[f] = v[k];
        }
        __syncthreads();
    }

    for (int i = tid; i < DIM; i += BLK) ws[i] = st[i];
}

// ---------------- kernel 2: per-sample layer 5 + CNOT perm, 8192 blocks --------
__global__ __launch_bounds__(BLK) void qnn_last_kernel(
    const float* __restrict__ X,      // (B, NQ)
    const float* __restrict__ P,      // (NL, NQ, 3)
    const float2* __restrict__ S5,    // shared state after layer 4
    float2* __restrict__ out)         // (B, DIM) float2
{
    __shared__ float2 lds[DIM];
    __shared__ float2 G[NQ][4];
    const int b   = blockIdx.x;
    const int tid = threadIdx.x;

    // fused gate table for layer 5: V = RY(x_q) * RZ(p2) RY(p1) RZ(p0)
    if (tid < NQ) {
        const int q  = tid;
        const int gi = (NL-1)*NQ + q;
        const float p0 = P[gi*3+0], p1 = P[gi*3+1], p2 = P[gi*3+2];
        const float t  = 0.5f*p1;
        const float c  = cosf(t),  s  = sinf(t);
        const float al = 0.5f*(p0+p2), be = 0.5f*(p0-p2);
        const float ca = cosf(al), sa = sinf(al);
        const float cb = cosf(be), sb = sinf(be);
        const float2 U00 = make_float2( c*ca, -c*sa);
        const float2 U01 = make_float2(-s*cb, -s*sb);
        const float2 U10 = make_float2( s*cb, -s*sb);
        const float2 U11 = make_float2( c*ca,  c*sa);
        const float tx = 0.5f * X[(size_t)b*NQ + q];
        const float cx = cosf(tx), sx = sinf(tx);
        G[q][0] = make_float2(cx*U00.x - sx*U10.x, cx*U00.y - sx*U10.y);
        G[q][1] = make_float2(cx*U01.x - sx*U11.x, cx*U01.y - sx*U11.y);
        G[q][2] = make_float2(sx*U00.x + cx*U10.x, sx*U00.y + cx*U10.y);
        G[q][3] = make_float2(sx*U01.x + cx*U11.x, sx*U01.y + cx*U11.y);
    }

    // load shared state, layout L0: reg r holds i = (r<<8)|t  (bits 10..8 local)
    float2 a[8];
    #pragma unroll
    for (int r = 0; r < 8; ++r) a[r] = S5[(r<<8) | tid];
    __syncthreads();   // gate table ready

    // gates on bits 10,9,8 = qubits 0,1,2 (r bits 2,1,0)
    #define RGATE(q_, rb_) { \
        const float2 U00=G[q_][0], U01=G[q_][1], U10=G[q_][2], U11=G[q_][3]; \
        _Pragma("unroll") \
        for (int rr = 0; rr < 8; ++rr) if (!(rr & (rb_))) { \
            const float2 a0 = a[rr], a1 = a[rr|(rb_)]; \
            a[rr]        = cfma2(U00, a0, U01, a1); \
            a[rr|(rb_)]  = cfma2(U10, a0, U11, a1); \
        } }
    RGATE(0, 4) RGATE(1, 2) RGATE(2, 1)

    // X1: relocalize to bits {7,6,5}:  i = (t[7:5]<<8)|(r<<5)|(t[4:0])
    #pragma unroll
    for (int r = 0; r < 8; ++r) lds[sw((r<<8) | tid)] = a[r];
    __syncthreads();
    #pragma unroll
    for (int r = 0; r < 8; ++r) a[r] = lds[sw(((tid>>5)<<8) | (r<<5) | (tid&31))];
    __syncthreads();
    RGATE(3, 4) RGATE(4, 2) RGATE(5, 1)   // qubits 3,4,5 = bits 7,6,5

    // X2: relocalize to bits {4,3,2}:  i = (t[7:2]<<5)|(r<<2)|(t[1:0])
    #pragma unroll
    for (int r = 0; r < 8; ++r) lds[sw(((tid>>5)<<8) | (r<<5) | (tid&31))] = a[r];
    __syncthreads();
    #pragma unroll
    for (int r = 0; r < 8; ++r) a[r] = lds[sw(((tid>>2)<<5) | (r<<2) | (tid&3))];
    __syncthreads();
    RGATE(6, 4) RGATE(7, 2) RGATE(8, 1)   // qubits 6,7,8 = bits 4,3,2

    // qubits 9,10 = bits 1,0 : lane bits -> shfl_xor, no barrier
    #pragma unroll
    for (int gq = 9; gq <= 10; ++gq) {
        const int m = (gq == 9) ? 2 : 1;
        const int bbit = (gq == 9) ? ((tid>>1)&1) : (tid&1);
        const float2 ca = bbit ? G[gq][3] : G[gq][0];
        const float2 cb = bbit ? G[gq][2] : G[gq][1];
        #pragma unroll
        for (int rr = 0; rr < 8; ++rr) {
            float2 p;
            p.x = __shfl_xor(a[rr].x, m);
            p.y = __shfl_xor(a[rr].y, m);
            a[rr] = cfma2(ca, a[rr], cb, p);
        }
    }

    // write back (L2 layout), then CNOT-perm gather + coalesced store
    #pragma unroll
    for (int r = 0; r < 8; ++r) lds[sw(((tid>>2)<<5) | (r<<2) | (tid&3))] = a[r];
    __syncthreads();

    float2* o = out + (size_t)b * DIM;
    #pragma unroll
    for (int r = 0; r < 8; ++r) {
        const int j = (tid<<3) | r;
        a[r] = lds[sw(j ^ (j >> 1))];   // T[j] = S[j ^ (j>>1)]
    }
    float4* o4 = (float4*)(o + (tid<<3));
    #pragma unroll
    for (int k = 0; k < 4; ++k)
        o4[k] = make_float4(a[2*k].x, a[2*k].y, a[2*k+1].x, a[2*k+1].y);
}

extern "C" void kernel_launch(void* const* d_in, const int* in_sizes, int n_in,
                              void* d_out, int out_size, void* d_ws, size_t ws_size,
                              hipStream_t stream) {
    const float* X = (const float*)d_in[0];   // (B, NQ) float32
    const float* P = (const float*)d_in[1];   // (NL, NQ, 3) float32
    float2* out = (float2*)d_out;
    float2* ws  = (float2*)d_ws;              // 16 KB shared state
    const int B = in_sizes[0] / NQ;           // 8192
    qnn_shared_kernel<<<1, BLK, 0, stream>>>(P, ws);
    qnn_last_kernel<<<B, BLK, 0, stream>>>(X, P, ws, out);
}

// Round 3
// 93.487 us; speedup vs baseline: 4.7666x; 1.2405x over previous
//
#include <hip/hip_runtime.h>
#include <math.h>

#define NQ   11
#define DIM  2048        // 2^11
#define NL   6
#define BLK  256

// Swizzle for kernel2 LDS rounds. Linear bijection on 11-bit indices:
// y4^=x10^x1, y3^=x9^x0, y2^=x8, y1^=x7, y0^=x6. Verified rank-5 over lane
// bits for all 6 write/read patterns below -> <=2-way bank access (free).
__device__ __forceinline__ int swz(int x) {
    return x ^ ((x >> 6) & 31) ^ ((x & 2) << 3) ^ ((x & 1) << 3);
}

__device__ __forceinline__ float2 cfma2(float2 u, float2 a, float2 v, float2 b) {
    float2 r;
    r.x = u.x*a.x - u.y*a.y + v.x*b.x - v.y*b.y;
    r.y = u.x*a.y + u.y*a.x + v.x*b.y + v.y*b.x;
    return r;
}

// ---- kernel 1: ALL sample-independent work, 1 block ----
// layers 0..4 (gates + CNOT perm) + layer 5's shared RZ RY RZ gates (no perm).
__global__ __launch_bounds__(BLK) void qnn_shared_kernel(
    const float* __restrict__ P,      // (NL, NQ, 3)
    float2* __restrict__ ws)          // out: 2048 float2
{
    __shared__ float2 st[DIM];
    __shared__ float2 G[NL*NQ][4];
    const int tid = threadIdx.x;

    for (int i = tid; i < DIM; i += BLK) st[i] = make_float2(0.f, 0.f);
    if (tid == 0) st[0] = make_float2(1.f, 0.f);

    if (tid < NL*NQ) {
        const float p0 = P[tid*3+0], p1 = P[tid*3+1], p2 = P[tid*3+2];
        const float t  = 0.5f*p1;
        const float c  = cosf(t),  s  = sinf(t);
        const float al = 0.5f*(p0+p2), be = 0.5f*(p0-p2);
        const float ca = cosf(al), sa = sinf(al);
        const float cb = cosf(be), sb = sinf(be);
        G[tid][0] = make_float2( c*ca, -c*sa);
        G[tid][1] = make_float2(-s*cb, -s*sb);
        G[tid][2] = make_float2( s*cb, -s*sb);
        G[tid][3] = make_float2( c*ca,  c*sa);
    }
    __syncthreads();

    for (int l = 0; l < NL; ++l) {
        for (int q = 0; q < NQ; ++q) {
            const int g = l*NQ + q;
            const float2 U00 = G[g][0], U01 = G[g][1], U10 = G[g][2], U11 = G[g][3];
            const int p    = NQ - 1 - q;
            const int mask = 1 << p;
            #pragma unroll
            for (int k = 0; k < 4; ++k) {
                const int j  = tid + k*BLK;
                const int i0 = ((j >> p) << (p+1)) | (j & (mask-1));
                const int i1 = i0 | mask;
                const float2 a0 = st[i0], a1 = st[i1];
                st[i0] = cfma2(U00, a0, U01, a1);
                st[i1] = cfma2(U10, a0, U11, a1);
            }
            __syncthreads();
        }
        if (l < NL-1) {
            // CNOT chain: amp at i moves to prefix-XOR f(i)
            float2 v[DIM/BLK];
            #pragma unroll
            for (int k = 0; k < DIM/BLK; ++k) v[k] = st[tid + k*BLK];
            __syncthreads();
            #pragma unroll
            for (int k = 0; k < DIM/BLK; ++k) {
                const int i = tid + k*BLK;
                int f = i;
                f ^= f >> 1; f ^= f >> 2; f ^= f >> 4; f ^= f >> 8;
                st[f] = v[k];
            }
            __syncthreads();
        }
    }

    for (int i = tid; i < DIM; i += BLK) ws[i] = st[i];
}

// ---- kernel 2: per-sample 11 real RY gates + CNOT perm, 8192 blocks ----
__global__ __launch_bounds__(BLK) void qnn_last_kernel(
    const float* __restrict__ X,      // (B, NQ)
    const float2* __restrict__ S5,    // shared state
    float2* __restrict__ out)         // (B, DIM)
{
    __shared__ float2 lds[DIM];
    __shared__ float2 gc[NQ];         // (cos, sin) of x_q/2
    const int b = blockIdx.x;
    const int t = threadIdx.x;

    if (t < NQ) {
        const float tx = 0.5f * X[(size_t)b*NQ + t];
        gc[t] = make_float2(cosf(tx), sinf(tx));
    }

    // load shared state: reg k holds state index i = (k<<8)|t (bits 10..8 local)
    float2 a[8];
    #pragma unroll
    for (int k = 0; k < 8; ++k) a[k] = S5[(k<<8) | t];
    __syncthreads();   // gc ready

    // real RY on reg-bit rb_, qubit q_:  n0 = c a0 - s a1 ; n1 = s a0 + c a1
    #define RGATE(q_, rb_) { \
        const float c = gc[q_].x, s = gc[q_].y; \
        _Pragma("unroll") \
        for (int kk = 0; kk < 8; ++kk) if (!(kk & (rb_))) { \
            const float2 a0 = a[kk], a1 = a[kk|(rb_)]; \
            a[kk]       = make_float2(c*a0.x - s*a1.x, c*a0.y - s*a1.y); \
            a[kk|(rb_)] = make_float2(s*a0.x + c*a1.x, s*a0.y + c*a1.y); \
        } }

    // perm-conjugated RY (after X3 gather), explicit (a0,a1) register roles
    #define CGATE(q_, i0_, i1_) { \
        const float c = gc[q_].x, s = gc[q_].y; \
        const float2 a0 = a[i0_], a1 = a[i1_]; \
        a[i0_] = make_float2(c*a0.x - s*a1.x, c*a0.y - s*a1.y); \
        a[i1_] = make_float2(s*a0.x + c*a1.x, s*a0.y + c*a1.y); \
    }

    RGATE(0, 4) RGATE(1, 2) RGATE(2, 1)      // qubits 0,1,2 = bits 10,9,8

    // X1: relocalize to bits {7,6,5}
    #pragma unroll
    for (int k = 0; k < 8; ++k) lds[swz((k<<8) | t)] = a[k];
    __syncthreads();
    #pragma unroll
    for (int k = 0; k < 8; ++k) a[k] = lds[swz(((t>>5)<<8) | (k<<5) | (t&31))];
    __syncthreads();
    RGATE(3, 4) RGATE(4, 2) RGATE(5, 1)      // qubits 3,4,5 = bits 7,6,5

    // X2: relocalize to bits {4,3,2}
    #pragma unroll
    for (int k = 0; k < 8; ++k) lds[swz(((t>>5)<<8) | (k<<5) | (t&31))] = a[k];
    __syncthreads();
    #pragma unroll
    for (int k = 0; k < 8; ++k) a[k] = lds[swz(((t>>2)<<5) | (k<<2) | (t&3))];
    __syncthreads();
    RGATE(6, 4) RGATE(7, 2) RGATE(8, 1)      // qubits 6,7,8 = bits 4,3,2

    // X3: CNOT-perm gather. reg k holds OUTPUT index i = (t<<3)|k,
    // gathered from state index g(i) = i ^ (i>>1).
    #pragma unroll
    for (int k = 0; k < 8; ++k) lds[swz(((t>>2)<<5) | (k<<2) | (t&3))] = a[k];
    __syncthreads();
    #pragma unroll
    for (int k = 0; k < 8; ++k) {
        const int i = (t<<3) | k;
        a[k] = lds[swz(i ^ (i >> 1))];
    }

    // qubit 9 (state bit 1) conjugated: pairs i <-> i^3, a0 where k1^k2==0
    CGATE(9, 0, 3) CGATE(9, 1, 2) CGATE(9, 7, 4) CGATE(9, 6, 5)
    // qubit 10 (state bit 0) conjugated: pairs i <-> i^1, a0 where k0^k1==0
    CGATE(10, 0, 1) CGATE(10, 3, 2) CGATE(10, 4, 5) CGATE(10, 7, 6)

    // store: thread t owns output amps (t<<3)..(t<<3)+7, 64 B contiguous
    float4* o4 = (float4*)(out + (size_t)b * DIM + (t<<3));
    #pragma unroll
    for (int k = 0; k < 4; ++k)
        o4[k] = make_float4(a[2*k].x, a[2*k].y, a[2*k+1].x, a[2*k+1].y);
}

extern "C" void kernel_launch(void* const* d_in, const int* in_sizes, int n_in,
                              void* d_out, int out_size, void* d_ws, size_t ws_size,
                              hipStream_t stream) {
    const float* X = (const float*)d_in[0];   // (B, NQ) float32
    const float* P = (const float*)d_in[1];   // (NL, NQ, 3) float32
    float2* out = (float2*)d_out;
    float2* ws  = (float2*)d_ws;              // 16 KB shared state
    const int B = in_sizes[0] / NQ;           // 8192
    qnn_shared_kernel<<<1, BLK, 0, stream>>>(P, ws);
    qnn_last_kernel<<<B, BLK, 0, stream>>>(X, ws, out);
}

// Round 4
// 60.382 us; speedup vs baseline: 7.3799x; 1.5483x over previous
//
#include <hip/hip_runtime.h>
#include <math.h>

#define NQ   11
#define DIM  2048        // 2^11
#define NL   6

// ---- swizzle for kernel1 (256-thread layouts), R3-proven ----
__device__ __forceinline__ int swzA(int x) {
    return x ^ ((x >> 6) & 31) ^ ((x & 2) << 3) ^ ((x & 1) << 3);
}
// ---- swizzle for kernel2 (128-thread layouts) ----
// B0=i0^i7, B1=i1^i4^i8, B2=i2^i5^i9, B3=i3^i6^i9 : rank-4 bank map for all
// four access patterns (L0 write, L1 r/w, L2 r/w, perm-gather read).
__device__ __forceinline__ int swzB(int x) {
    return x ^ ((x >> 7) & 7) ^ ((x >> 3) & 14) ^ ((x >> 6) & 8);
}

__device__ __forceinline__ float2 cfma2(float2 u, float2 a, float2 v, float2 b) {
    float2 r;
    r.x = u.x*a.x - u.y*a.y + v.x*b.x - v.y*b.y;
    r.y = u.x*a.y + u.y*a.x + v.x*b.y + v.y*b.x;
    return r;
}

// ================= kernel 1: all sample-independent work, 1 block ============
// layers 0..4 (gates + CNOT perm) + layer 5 shared RZ·RY·RZ gates (no perm).
// Register-blocked: 256 threads x 8 amps; 3 LDS exchanges + 2 shfl gates/layer.
__global__ __launch_bounds__(256) void qnn_shared_kernel(
    const float* __restrict__ P,      // (NL, NQ, 3)
    float2* __restrict__ ws)          // out: 2048 float2, natural order
{
    __shared__ float2 lds[DIM];
    __shared__ float2 G[NL*NQ][4];
    const int t = threadIdx.x;        // 8 bits

    if (t < NL*NQ) {
        const float p0 = P[t*3+0], p1 = P[t*3+1], p2 = P[t*3+2];
        const float th = 0.5f*p1;
        const float c  = cosf(th), s = sinf(th);
        const float al = 0.5f*(p0+p2), be = 0.5f*(p0-p2);
        const float ca = cosf(al), sa = sinf(al);
        const float cb = cosf(be), sb = sinf(be);
        G[t][0] = make_float2( c*ca, -c*sa);
        G[t][1] = make_float2(-s*cb, -s*sb);
        G[t][2] = make_float2( s*cb, -s*sb);
        G[t][3] = make_float2( c*ca,  c*sa);
    }

    // |0...0> in registers, layout L0: reg k holds amp i=(k<<8)|t
    float2 a[8];
    #pragma unroll
    for (int k = 0; k < 8; ++k) a[k] = make_float2(0.f, 0.f);
    if (t == 0) a[0] = make_float2(1.f, 0.f);
    __syncthreads();   // G ready

    // complex gate from table on reg bit rb
    #define CG(g_, rb_) { \
        const float2 U00=G[g_][0], U01=G[g_][1], U10=G[g_][2], U11=G[g_][3]; \
        _Pragma("unroll") \
        for (int kk = 0; kk < 8; ++kk) if (!(kk & (rb_))) { \
            const float2 a0 = a[kk], a1 = a[kk|(rb_)]; \
            a[kk]       = cfma2(U00, a0, U01, a1); \
            a[kk|(rb_)] = cfma2(U10, a0, U11, a1); \
        } }

    // complex gate on lane bit (mask m_), role bit b_
    #define SG(g_, m_, b_) { \
        const float2 ca_ = (b_) ? G[g_][3] : G[g_][0]; \
        const float2 cb_ = (b_) ? G[g_][2] : G[g_][1]; \
        _Pragma("unroll") \
        for (int kk = 0; kk < 8; ++kk) { \
            float2 p; \
            p.x = __shfl_xor(a[kk].x, m_); \
            p.y = __shfl_xor(a[kk].y, m_); \
            a[kk] = cfma2(ca_, a[kk], cb_, p); \
        } }

    for (int l = 0; l < NL; ++l) {
        const int g0 = l*NQ;
        CG(g0+0, 4) CG(g0+1, 2) CG(g0+2, 1)          // qubits 0,1,2 (bits 10,9,8)

        // X1 -> L1: i = (t[7:5]<<8)|(k<<5)|t[4:0]
        #pragma unroll
        for (int k = 0; k < 8; ++k) lds[swzA((k<<8) | t)] = a[k];
        __syncthreads();
        #pragma unroll
        for (int k = 0; k < 8; ++k) a[k] = lds[swzA(((t>>5)<<8) | (k<<5) | (t&31))];
        __syncthreads();
        CG(g0+3, 4) CG(g0+4, 2) CG(g0+5, 1)          // qubits 3,4,5 (bits 7,6,5)

        // X2 -> L2: i = (t[7:2]<<5)|(k<<2)|t[1:0]
        #pragma unroll
        for (int k = 0; k < 8; ++k) lds[swzA(((t>>5)<<8) | (k<<5) | (t&31))] = a[k];
        __syncthreads();
        #pragma unroll
        for (int k = 0; k < 8; ++k) a[k] = lds[swzA(((t>>2)<<5) | (k<<2) | (t&3))];
        __syncthreads();
        CG(g0+6, 4) CG(g0+7, 2) CG(g0+8, 1)          // qubits 6,7,8 (bits 4,3,2)

        // qubits 9,10 (bits 1,0 = lane bits): shfl gates
        SG(g0+9, 2, (t>>1)&1)
        SG(g0+10, 1, t&1)

        if (l < NL-1) {
            // X3: CNOT perm (gather src = o^(o>>1)) + relocalize to L0
            #pragma unroll
            for (int k = 0; k < 8; ++k) lds[swzA(((t>>2)<<5) | (k<<2) | (t&3))] = a[k];
            __syncthreads();
            #pragma unroll
            for (int k = 0; k < 8; ++k) {
                const int oi = (k<<8) | t;
                a[k] = lds[swzA(oi ^ (oi >> 1))];
            }
            __syncthreads();
        } else {
            // layer 5: no perm; write ws in natural order from L2 layout
            #pragma unroll
            for (int k = 0; k < 8; ++k)
                ws[((t>>2)<<5) | (k<<2) | (t&3)] = a[k];
        }
    }
    #undef CG
    #undef SG
}

// ========= kernel 2: per-sample 11 real RY gates + CNOT perm, 8192 blocks ====
// 128 threads x 16 amps; 3 exchanges; final layout lane-major -> coalesced st.
__global__ __launch_bounds__(128, 4) void qnn_last_kernel(
    const float* __restrict__ X,      // (B, NQ)
    const float2* __restrict__ S5,    // shared state, natural order
    float2* __restrict__ out)         // (B, DIM)
{
    __shared__ float2 lds[DIM];
    __shared__ float2 gc[NQ];
    const int b = blockIdx.x;
    const int t = threadIdx.x;        // 7 bits

    if (t < NQ) {
        const float tx = 0.5f * X[(size_t)b*NQ + t];
        gc[t] = make_float2(cosf(tx), sinf(tx));
    }

    // L0: reg k holds amp i = (k<<7)|t  (bits 10..7 local)
    float2 a[16];
    #pragma unroll
    for (int k = 0; k < 16; ++k) a[k] = S5[(k<<7) | t];
    __syncthreads();   // gc ready

    // real RY on reg bit rb
    #define RG(q_, rb_) { \
        const float c = gc[q_].x, s = gc[q_].y; \
        _Pragma("unroll") \
        for (int kk = 0; kk < 16; ++kk) if (!(kk & (rb_))) { \
            const float2 a0 = a[kk], a1 = a[kk|(rb_)]; \
            a[kk]       = make_float2(c*a0.x - s*a1.x, c*a0.y - s*a1.y); \
            a[kk|(rb_)] = make_float2(s*a0.x + c*a1.x, s*a0.y + c*a1.y); \
        } }

    RG(0, 8) RG(1, 4) RG(2, 2) RG(3, 1)              // qubits 0..3 (bits 10..7)

    // X1 -> L1: i = (t[6:3]<<7)|(k<<3)|t[2:0]
    #pragma unroll
    for (int k = 0; k < 16; ++k) lds[swzB((k<<7) | t)] = a[k];
    __syncthreads();
    #pragma unroll
    for (int k = 0; k < 16; ++k) a[k] = lds[swzB(((t>>3)<<7) | (k<<3) | (t&7))];
    __syncthreads();
    RG(4, 8) RG(5, 4) RG(6, 2) RG(7, 1)              // qubits 4..7 (bits 6..3)

    // X2 -> L2: i = (t<<4)|k  (bits 3..0 local)
    #pragma unroll
    for (int k = 0; k < 16; ++k) lds[swzB(((t>>3)<<7) | (k<<3) | (t&7))] = a[k];
    __syncthreads();
    #pragma unroll
    for (int k = 0; k < 16; ++k) a[k] = lds[swzB((t<<4) | k)];
    __syncthreads();
    RG(8, 4) RG(9, 2) RG(10, 1)                      // qubits 8,9,10 (bits 2,1,0)

    // X3: CNOT perm + relocalize to lane-major store layout o=(k<<7)|t
    #pragma unroll
    for (int k = 0; k < 16; ++k) lds[swzB((t<<4) | k)] = a[k];
    __syncthreads();
    float2* o = out + (size_t)b * DIM;
    #pragma unroll
    for (int k = 0; k < 16; ++k) {
        const int oi = (k<<7) | t;
        o[oi] = lds[swzB(oi ^ (oi >> 1))];   // fully coalesced 512B/wave stores
    }
    #undef RG
}

extern "C" void kernel_launch(void* const* d_in, const int* in_sizes, int n_in,
                              void* d_out, int out_size, void* d_ws, size_t ws_size,
                              hipStream_t stream) {
    const float* X = (const float*)d_in[0];   // (B, NQ) float32
    const float* P = (const float*)d_in[1];   // (NL, NQ, 3) float32
    float2* out = (float2*)d_out;
    float2* ws  = (float2*)d_ws;              // 16 KB shared state
    const int B = in_sizes[0] / NQ;           // 8192
    qnn_shared_kernel<<<1, 256, 0, stream>>>(P, ws);
    qnn_last_kernel<<<B, 128, 0, stream>>>(X, ws, out);
}

// Round 5
// 52.758 us; speedup vs baseline: 8.4464x; 1.1445x over previous
//
#include <hip/hip_runtime.h>
#include <math.h>

#define NQ   11
#define DIM  2048        // 2^11
#define NL   6

// GF(2)-linear swizzles: swz(a^b) = swz(a)^swz(b); disjoint-field indices
// split into per-thread base XOR compile-time constant per unrolled k.
__host__ __device__ constexpr int swzA(int x) {
    return x ^ ((x >> 6) & 31) ^ ((x & 2) << 3) ^ ((x & 1) << 3);
}
__host__ __device__ constexpr int swzB(int x) {
    return x ^ ((x >> 7) & 7) ^ ((x >> 3) & 14) ^ ((x >> 6) & 8);
}

__device__ __forceinline__ float2 cfma2(float2 u, float2 a, float2 v, float2 b) {
    float2 r;
    r.x = u.x*a.x - u.y*a.y + v.x*b.x - v.y*b.y;
    r.y = u.x*a.y + u.y*a.x + v.x*b.y + v.y*b.x;
    return r;
}

// ================= kernel 1: all sample-independent work, 1 block ============
__global__ __launch_bounds__(256) void qnn_shared_kernel(
    const float* __restrict__ P,      // (NL, NQ, 3)
    float2* __restrict__ ws)          // out: 2048 float2, natural order
{
    __shared__ float2 lds[DIM];
    __shared__ float2 G[NL*NQ][4];
    const int t = threadIdx.x;        // 8 bits

    if (t < NL*NQ) {
        const float p0 = P[t*3+0], p1 = P[t*3+1], p2 = P[t*3+2];
        const float th = 0.5f*p1;
        const float c  = cosf(th), s = sinf(th);
        const float al = 0.5f*(p0+p2), be = 0.5f*(p0-p2);
        const float ca = cosf(al), sa = sinf(al);
        const float cb = cosf(be), sb = sinf(be);
        G[t][0] = make_float2( c*ca, -c*sa);
        G[t][1] = make_float2(-s*cb, -s*sb);
        G[t][2] = make_float2( s*cb, -s*sb);
        G[t][3] = make_float2( c*ca,  c*sa);
    }

    // per-thread LDS bases (swizzled), one-time cost
    const int a0w = swzA(t);                          // X1 write
    const int a1b = swzA(((t>>5)<<8) | (t&31));       // X1 read / X2 write
    const int a2b = swzA(((t>>2)<<5) | (t&3));        // X2 read / X3 write
    const int a3b = swzA(t ^ (t>>1));                 // X3 perm-gather read
    const int natb = ((t>>2)<<5) | (t&3);             // ws natural-order base

    float2 a[8];
    #pragma unroll
    for (int k = 0; k < 8; ++k) a[k] = make_float2(0.f, 0.f);
    if (t == 0) a[0] = make_float2(1.f, 0.f);
    __syncthreads();   // G ready

    #define CG(g_, rb_) { \
        const float2 U00=G[g_][0], U01=G[g_][1], U10=G[g_][2], U11=G[g_][3]; \
        _Pragma("unroll") \
        for (int kk = 0; kk < 8; ++kk) if (!(kk & (rb_))) { \
            const float2 a0 = a[kk], a1 = a[kk|(rb_)]; \
            a[kk]       = cfma2(U00, a0, U01, a1); \
            a[kk|(rb_)] = cfma2(U10, a0, U11, a1); \
        } }

    #define SG(g_, m_, b_) { \
        const float2 ca_ = (b_) ? G[g_][3] : G[g_][0]; \
        const float2 cb_ = (b_) ? G[g_][2] : G[g_][1]; \
        _Pragma("unroll") \
        for (int kk = 0; kk < 8; ++kk) { \
            float2 p; \
            p.x = __shfl_xor(a[kk].x, m_); \
            p.y = __shfl_xor(a[kk].y, m_); \
            a[kk] = cfma2(ca_, a[kk], cb_, p); \
        } }

    for (int l = 0; l < NL; ++l) {
        const int g0 = l*NQ;
        CG(g0+0, 4) CG(g0+1, 2) CG(g0+2, 1)          // qubits 0,1,2 (bits 10,9,8)

        #pragma unroll
        for (int k = 0; k < 8; ++k) lds[a0w ^ swzA(k<<8)] = a[k];
        __syncthreads();
        #pragma unroll
        for (int k = 0; k < 8; ++k) a[k] = lds[a1b ^ swzA(k<<5)];
        __syncthreads();
        CG(g0+3, 4) CG(g0+4, 2) CG(g0+5, 1)          // qubits 3,4,5 (bits 7,6,5)

        #pragma unroll
        for (int k = 0; k < 8; ++k) lds[a1b ^ swzA(k<<5)] = a[k];
        __syncthreads();
        #pragma unroll
        for (int k = 0; k < 8; ++k) a[k] = lds[a2b ^ swzA(k<<2)];
        __syncthreads();
        CG(g0+6, 4) CG(g0+7, 2) CG(g0+8, 1)          // qubits 6,7,8 (bits 4,3,2)

        SG(g0+9, 2, (t>>1)&1)                        // qubit 9 (bit 1)
        SG(g0+10, 1, t&1)                            // qubit 10 (bit 0)

        if (l < NL-1) {
            #pragma unroll
            for (int k = 0; k < 8; ++k) lds[a2b ^ swzA(k<<2)] = a[k];
            __syncthreads();
            #pragma unroll
            for (int k = 0; k < 8; ++k)
                a[k] = lds[a3b ^ swzA((k<<8) ^ (k<<7))];   // src = g((k<<8)|t)
            __syncthreads();
        } else {
            #pragma unroll
            for (int k = 0; k < 8; ++k) ws[natb | (k<<2)] = a[k];
        }
    }
    #undef CG
    #undef SG
}

// ========= kernel 2: per-sample 11 real RY gates + CNOT perm, 8192 blocks ====
__global__ __launch_bounds__(128, 4) void qnn_last_kernel(
    const float* __restrict__ X,      // (B, NQ)
    const float2* __restrict__ S5,    // shared state, natural order
    float2* __restrict__ out)         // (B, DIM)
{
    __shared__ float2 lds[DIM];
    __shared__ float2 gc[NQ];
    const int b = blockIdx.x;
    const int t = threadIdx.x;        // 7 bits

    if (t < NQ) {
        const float tx = 0.5f * X[(size_t)b*NQ + t];
        gc[t] = make_float2(cosf(tx), sinf(tx));
    }

    // per-thread LDS bases (swizzled)
    const int b0 = swzB(t);                           // L0 write
    const int b1 = swzB(((t>>3)<<7) | (t&7));         // L1 read / write
    const int b2 = swzB(t<<4);                        // L2 read / write
    const int b3 = swzB(t ^ (t>>1));                  // X3 perm-gather read

    // L0: reg k holds amp i = (k<<7)|t
    float2 a[16];
    #pragma unroll
    for (int k = 0; k < 16; ++k) a[k] = S5[(k<<7) | t];
    __syncthreads();   // gc ready

    // real RY on reg bit rb: paired-component shape (pk_fma-friendly)
    #define RG(q_, rb_) { \
        const float c = gc[q_].x, s = gc[q_].y; \
        _Pragma("unroll") \
        for (int kk = 0; kk < 16; ++kk) if (!(kk & (rb_))) { \
            const float2 a0 = a[kk], a1 = a[kk|(rb_)]; \
            float2 n0, n1; \
            n0.x = fmaf(c, a0.x, -s*a1.x); \
            n0.y = fmaf(c, a0.y, -s*a1.y); \
            n1.x = fmaf(s, a0.x,  c*a1.x); \
            n1.y = fmaf(s, a0.y,  c*a1.y); \
            a[kk] = n0; a[kk|(rb_)] = n1; \
        } }

    RG(0, 8) RG(1, 4) RG(2, 2) RG(3, 1)              // qubits 0..3 (bits 10..7)

    // X1 -> L1: i = (t[6:3]<<7)|(k<<3)|t[2:0]
    #pragma unroll
    for (int k = 0; k < 16; ++k) lds[b0 ^ swzB(k<<7)] = a[k];
    __syncthreads();
    #pragma unroll
    for (int k = 0; k < 16; ++k) a[k] = lds[b1 ^ swzB(k<<3)];
    __syncthreads();
    RG(4, 8) RG(5, 4) RG(6, 2) RG(7, 1)              // qubits 4..7 (bits 6..3)

    // X2 -> L2: i = (t<<4)|k
    #pragma unroll
    for (int k = 0; k < 16; ++k) lds[b1 ^ swzB(k<<3)] = a[k];
    __syncthreads();
    #pragma unroll
    for (int k = 0; k < 16; ++k) a[k] = lds[b2 ^ swzB(k)];
    __syncthreads();
    RG(8, 4) RG(9, 2) RG(10, 1)                      // qubits 8,9,10 (bits 2,1,0)

    // X3: CNOT perm + relocalize to lane-major store layout o=(k<<7)|t
    #pragma unroll
    for (int k = 0; k < 16; ++k) lds[b2 ^ swzB(k)] = a[k];
    __syncthreads();
    float2* o = out + (size_t)b * DIM + t;
    #pragma unroll
    for (int k = 0; k < 16; ++k)
        o[k<<7] = lds[b3 ^ swzB((k<<7) ^ (k<<6))];   // src = g((k<<7)|t)
    #undef RG
}

extern "C" void kernel_launch(void* const* d_in, const int* in_sizes, int n_in,
                              void* d_out, int out_size, void* d_ws, size_t ws_size,
                              hipStream_t stream) {
    const float* X = (const float*)d_in[0];   // (B, NQ) float32
    const float* P = (const float*)d_in[1];   // (NL, NQ, 3) float32
    float2* out = (float2*)d_out;
    float2* ws  = (float2*)d_ws;              // 16 KB shared state
    const int B = in_sizes[0] / NQ;           // 8192
    qnn_shared_kernel<<<1, 256, 0, stream>>>(P, ws);
    qnn_last_kernel<<<B, 128, 0, stream>>>(X, ws, out);
}